// Round 7
// baseline (746.053 us; speedup 1.0000x reference)
//
#include <hip/hip_runtime.h>

// ---------------------------------------------------------------------------
// RPN forward: conv3x3(512->512)+relu, 1x1 heads (18 cls, 36 bbox),
// anchor decode + clip, softmax score, greedy NMS (0.7), keep-masked boxes.
// All decision math in fp32 with contraction OFF to track the numpy reference.
// R7 scan: software-pipelined 16-wave scan. Per stripe s: (1) all waves ISSUE
//   raw loads of column s+1 (consumption deferred -> loads stay in flight
//   under the chain; T14 async-split), (2) masked reduce of column s from
//   LDS, (3) wave 0 ctz chain, (4) ds_write column s+1 into double buffer.
//   History: R1 scratch 517us; R2/R3 in-wave load serialization 655/536us;
//   R4 asm batches 434us; R5 global_load_lds same-wave readback WRONG (648);
//   R6 unpipelined TLP 372us (chain + load latency + barriers all serial).
// ---------------------------------------------------------------------------

#define NBATCH 4
#define HWDIM  25
#define NPOS   625            // 25*25
#define NM     2500           // NBATCH*NPOS
#define CIN    512
#define NANCH  5625           // NPOS*9
#define NW     88             // ceil(NANCH/64)
#define RSTR   5632           // row stride (64-aligned) for transposed mask
#define NWAVES 16

typedef unsigned long long u64;
typedef unsigned int u32;

struct BaseAnchors { float x1[9], y1[9], x2[9], y2[9]; };

__device__ __forceinline__ u64 bcast64(u64 v, int lane) {
  unsigned int lo = (unsigned int)v;
  unsigned int hi = (unsigned int)(v >> 32);
  lo = (unsigned int)__builtin_amdgcn_readlane((int)lo, lane);
  hi = (unsigned int)__builtin_amdgcn_readlane((int)hi, lane);
  return (((u64)hi) << 32) | (u64)lo;
}

__device__ __forceinline__ u64 waveOr64(u64 x) {
  unsigned int lo = (unsigned int)x, hi = (unsigned int)(x >> 32);
#pragma unroll
  for (int off = 32; off > 0; off >>= 1) {
    lo |= (unsigned int)__shfl_xor((int)lo, off, 64);
    hi |= (unsigned int)__shfl_xor((int)hi, off, 64);
  }
  return (((u64)hi) << 32) | (u64)lo;
}

// --------------------------- prep: transposes ------------------------------

// f[b][c][pos] -> fm[b*625+pos][c]
__global__ void transpose_features(const float* __restrict__ f, float* __restrict__ fm) {
  __shared__ float tile[32][33];
  int b  = blockIdx.z;
  int p0 = blockIdx.x * 32;
  int c0 = blockIdx.y * 32;
  int tx = threadIdx.x, ty = threadIdx.y;  // (32, 8)
#pragma unroll
  for (int j = 0; j < 4; j++) {
    int c = c0 + ty + j * 8;
    int p = p0 + tx;
    if (p < NPOS) tile[ty + j * 8][tx] = f[((size_t)(b * CIN + c)) * NPOS + p];
  }
  __syncthreads();
#pragma unroll
  for (int j = 0; j < 4; j++) {
    int p = p0 + ty + j * 8;
    int c = c0 + tx;
    if (p < NPOS) fm[((size_t)(b * NPOS + p)) * CIN + c] = tile[tx][ty + j * 8];
  }
}

// conv_w[o][c][tap] -> Wt[tap][c][o]
__global__ __launch_bounds__(256) void transpose_weights(const float* __restrict__ cw,
                                                         float* __restrict__ Wt) {
  __shared__ float tile[32][289];
  int o0 = blockIdx.x * 32, c0 = blockIdx.y * 32;
  int tid = threadIdx.x;
#pragma unroll
  for (int j = 0; j < 36; j++) {
    int idx = tid + j * 256;            // 0..9215
    int o = idx / 288, kk = idx % 288;  // kk = c_rel*9 + tap
    tile[o][kk] = cw[((size_t)(o0 + o)) * 4608 + c0 * 9 + kk];
  }
  __syncthreads();
  int ol = tid & 31, pg = tid >> 5;  // 0..7
#pragma unroll
  for (int j = 0; j < 36; j++) {
    int pair = pg + j * 8;  // 0..287 == c_rel*9 + tap
    int c = pair / 9, tap = pair % 9;
    Wt[((size_t)tap * CIN + (c0 + c)) * 512 + o0 + ol] = tile[ol][pair];
  }
}

// combined 1x1 head weights: Wco[c][o] (o: 0..17 cls, 18..53 bbox, 54..63 zero)
__global__ void build_wco(const float* __restrict__ clsw, const float* __restrict__ clsb,
                          const float* __restrict__ bw, const float* __restrict__ bbb,
                          float* __restrict__ Wco, float* __restrict__ bco) {
  int idx = blockIdx.x * 256 + threadIdx.x;
  if (idx < 512 * 64) {
    int c = idx >> 6, o = idx & 63;
    float v = 0.f;
    if (o < 18) v = clsw[o * 512 + c];
    else if (o < 54) v = bw[(o - 18) * 512 + c];
    Wco[idx] = v;
  }
  if (idx < 64) {
    float v = 0.f;
    if (idx < 18) v = clsb[idx];
    else if (idx < 54) v = bbb[idx - 18];
    bco[idx] = v;
  }
}

// --------------------------- conv3x3 implicit GEMM -------------------------
// grid (40, 8, 3): 64 m-rows x 64 o-cols per block, part = 3 taps (dy fixed).
// Writes partial sums (no bias/relu) to xp[part][m][o].
__global__ __launch_bounds__(256) void conv_gemm(const float* __restrict__ fm,
                                                 const float* __restrict__ Wt,
                                                 float* __restrict__ xp) {
  __shared__ __align__(16) float At[32][68];
  __shared__ __align__(16) float Bt[32][64];
  int tid = threadIdx.x;
  int m0 = blockIdx.x << 6;
  int o0 = blockIdx.y << 6;
  int part = blockIdx.z;  // 0..2 -> dy = part-1
  int ti = tid >> 4, tj = tid & 15;   // compute tile 4x4
  int si = tid >> 2, sq = tid & 3;    // A staging: row si, col quad sq
  int skk = tid >> 3, sr = tid & 7;   // B staging: k-row skk, col oct sr
  float acc[4][4] = {{0.f}};

  int m = m0 + si;
  bool mv = m < NM;
  int mm = mv ? m : 0;
  int bb = mm / NPOS, rem = mm % NPOS;
  int hh = rem / HWDIM, ww = rem % HWDIM;
  int dy = part - 1;

  for (int tt = 0; tt < 3; tt++) {
    int tap = part * 3 + tt;
    int dx = tt - 1;
    int h2 = hh + dy, w2 = ww + dx;
    bool av = mv && ((unsigned)h2 < (unsigned)HWDIM) && ((unsigned)w2 < (unsigned)HWDIM);
    const float* arow = fm + (((size_t)(bb * NPOS + h2 * HWDIM + w2)) << 9);
    const float* bbase = Wt + (((size_t)tap) << 18) + o0;
    for (int c0 = 0; c0 < CIN; c0 += 32) {
      __syncthreads();
      float4 a0 = make_float4(0.f, 0.f, 0.f, 0.f), a1 = a0;
      if (av) {
        a0 = *(const float4*)(arow + c0 + (sq << 2));
        a1 = *(const float4*)(arow + c0 + 16 + (sq << 2));
      }
      int kb = sq << 2;
      At[kb + 0][si] = a0.x; At[kb + 1][si] = a0.y; At[kb + 2][si] = a0.z; At[kb + 3][si] = a0.w;
      At[kb + 16][si] = a1.x; At[kb + 17][si] = a1.y; At[kb + 18][si] = a1.z; At[kb + 19][si] = a1.w;
      const float* bp = bbase + (((size_t)(c0 + skk)) << 9);
      *(float4*)&Bt[skk][sr << 2] = *(const float4*)(bp + (sr << 2));
      *(float4*)&Bt[skk][32 + (sr << 2)] = *(const float4*)(bp + 32 + (sr << 2));
      __syncthreads();
#pragma unroll
      for (int kk = 0; kk < 32; kk++) {
        float4 avv = *(const float4*)&At[kk][ti << 2];
        float4 bvv = *(const float4*)&Bt[kk][tj << 2];
        float a_[4] = {avv.x, avv.y, avv.z, avv.w};
        float b_[4] = {bvv.x, bvv.y, bvv.z, bvv.w};
#pragma unroll
        for (int u = 0; u < 4; u++)
#pragma unroll
          for (int v = 0; v < 4; v++) acc[u][v] += a_[u] * b_[v];
      }
    }
  }
  float* outp = xp + (size_t)part * (NM * 512);
#pragma unroll
  for (int u = 0; u < 4; u++) {
    int mr = m0 + (ti << 2) + u;
    if (mr < NM) {
      float4 r = make_float4(acc[u][0], acc[u][1], acc[u][2], acc[u][3]);
      *(float4*)(outp + (((size_t)mr) << 9) + o0 + (tj << 2)) = r;
    }
  }
}

// x2 = relu(xp0+xp1+xp2+bias)
__global__ void combine_relu(const float* __restrict__ xp, const float* __restrict__ bias,
                             float* __restrict__ x2) {
  int i4 = blockIdx.x * 256 + threadIdx.x;  // over 320000 float4s
  if (i4 >= NM * 128) return;
  float4 p0 = *(const float4*)(xp + (size_t)i4 * 4);
  float4 p1 = *(const float4*)(xp + (size_t)(NM * 512) + (size_t)i4 * 4);
  float4 p2 = *(const float4*)(xp + (size_t)(2 * NM * 512) + (size_t)i4 * 4);
  float4 bb = *(const float4*)(bias + (i4 & 127) * 4);
  float4 r;
  r.x = fmaxf(p0.x + p1.x + p2.x + bb.x, 0.f);
  r.y = fmaxf(p0.y + p1.y + p2.y + bb.y, 0.f);
  r.z = fmaxf(p0.z + p1.z + p2.z + bb.z, 0.f);
  r.w = fmaxf(p0.w + p1.w + p2.w + bb.w, 0.f);
  *(float4*)(x2 + (size_t)i4 * 4) = r;
}

// --------------------------- 1x1 heads GEMM --------------------------------
// logits[m][0..63] = x2[m][:] @ Wco + bco   (grid 40)
__global__ __launch_bounds__(256) void gemm1x1(const float* __restrict__ x2,
                                               const float* __restrict__ Wco,
                                               const float* __restrict__ bco,
                                               float* __restrict__ logits) {
  __shared__ __align__(16) float At[32][68];
  __shared__ __align__(16) float Bt[32][64];
  int tid = threadIdx.x;
  int m0 = blockIdx.x << 6;
  int ti = tid >> 4, tj = tid & 15;
  int si = tid >> 2, sq = tid & 3;
  int skk = tid >> 3, sr = tid & 7;
  float acc[4][4] = {{0.f}};
  int m = m0 + si;
  bool mv = m < NM;
  const float* arow = x2 + (((size_t)(mv ? m : 0)) << 9);
  for (int c0 = 0; c0 < CIN; c0 += 32) {
    __syncthreads();
    float4 a0 = make_float4(0.f, 0.f, 0.f, 0.f), a1 = a0;
    if (mv) {
      a0 = *(const float4*)(arow + c0 + (sq << 2));
      a1 = *(const float4*)(arow + c0 + 16 + (sq << 2));
    }
    int kb = sq << 2;
    At[kb + 0][si] = a0.x; At[kb + 1][si] = a0.y; At[kb + 2][si] = a0.z; At[kb + 3][si] = a0.w;
    At[kb + 16][si] = a1.x; At[kb + 17][si] = a1.y; At[kb + 18][si] = a1.z; At[kb + 19][si] = a1.w;
    const float* bp = Wco + (size_t)(c0 + skk) * 64;
    *(float4*)&Bt[skk][sr << 2] = *(const float4*)(bp + (sr << 2));
    *(float4*)&Bt[skk][32 + (sr << 2)] = *(const float4*)(bp + 32 + (sr << 2));
    __syncthreads();
#pragma unroll
    for (int kk = 0; kk < 32; kk++) {
      float4 avv = *(const float4*)&At[kk][ti << 2];
      float4 bvv = *(const float4*)&Bt[kk][tj << 2];
      float a_[4] = {avv.x, avv.y, avv.z, avv.w};
      float b_[4] = {bvv.x, bvv.y, bvv.z, bvv.w};
#pragma unroll
      for (int u = 0; u < 4; u++)
#pragma unroll
        for (int v = 0; v < 4; v++) acc[u][v] += a_[u] * b_[v];
    }
  }
  float4 bias = *(const float4*)(bco + (tj << 2));
#pragma unroll
  for (int u = 0; u < 4; u++) {
    int mr = m0 + (ti << 2) + u;
    if (mr < NM) {
      float4 r = make_float4(acc[u][0] + bias.x, acc[u][1] + bias.y, acc[u][2] + bias.z,
                             acc[u][3] + bias.w);
      *(float4*)(logits + (size_t)mr * 64 + (tj << 2)) = r;
    }
  }
}

// --------------------------- scores + proposals ----------------------------
__global__ __launch_bounds__(256) void score_box_kernel(const float* __restrict__ logits,
                                                        const int* __restrict__ ih,
                                                        const int* __restrict__ iw,
                                                        BaseAnchors ba,
                                                        float* __restrict__ scores,
                                                        float* __restrict__ props) {
#pragma clang fp contract(off)
  int n = blockIdx.x * 256 + threadIdx.x;
  if (n >= NBATCH * NANCH) return;
  int b = n / NANCH;
  int r = n % NANCH;
  int pos = r / 9, aa = r % 9;
  int py = pos / HWDIM, px = pos % HWDIM;
  const float* L = logits + (size_t)(b * NPOS + pos) * 64;
  float l0 = L[2 * aa], l1 = L[2 * aa + 1];
  float mx = fmaxf(l0, l1);
  float e0 = expf(l0 - mx), e1 = expf(l1 - mx);
  float s = e1 / (e0 + e1);
  float d0 = L[18 + 4 * aa + 0], d1 = L[18 + 4 * aa + 1];
  float d2 = L[18 + 4 * aa + 2], d3 = L[18 + 4 * aa + 3];
  float xf = (float)px * 32.f, yf = (float)py * 32.f;
  float ax1 = ba.x1[aa] + xf, ay1 = ba.y1[aa] + yf;
  float ax2 = ba.x2[aa] + xf, ay2 = ba.y2[aa] + yf;
  float wA = ax2 - ax1, hA = ay2 - ay1;
  float cx = ax1 + 0.5f * wA, cy = ay1 + 0.5f * hA;
  float pcx = d0 * wA + cx, pcy = d1 * hA + cy;
  float pw = expf(d2) * wA, ph = expf(d3) * hA;
  float x1 = pcx - 0.5f * pw, y1 = pcy - 0.5f * ph;
  float x2 = pcx + 0.5f * pw, y2 = pcy + 0.5f * ph;
  float W = (float)iw[0], H = (float)ih[0];
  x1 = fminf(fmaxf(x1, 0.f), W);
  y1 = fminf(fmaxf(y1, 0.f), H);
  x2 = fminf(fmaxf(x2, 0.f), W);
  y2 = fminf(fmaxf(y2, 0.f), H);
  scores[n] = s;
  *(float4*)(props + (size_t)n * 4) = make_float4(x1, y1, x2, y2);
}

// --------------------------- sort (bitonic, stable ties) -------------------
__global__ __launch_bounds__(1024) void sort_kernel(const float* __restrict__ scores,
                                                    const float* __restrict__ props,
                                                    int* __restrict__ order,
                                                    float* __restrict__ sb) {
  __shared__ u64 keys[8192];
  int b = blockIdx.x, tid = threadIdx.x;
  const float* sc = scores + (size_t)b * NANCH;
  for (int i = tid; i < 8192; i += 1024) {
    u64 k = 0ull;
    if (i < NANCH) {
      unsigned int sbits = __float_as_uint(sc[i]);  // scores > 0 -> order-preserving bits
      k = (((u64)sbits) << 32) | (u64)(~(unsigned int)i);
    }
    keys[i] = k;
  }
  __syncthreads();
  for (int k = 2; k <= 8192; k <<= 1) {
    for (int j = k >> 1; j > 0; j >>= 1) {
#pragma unroll
      for (int s = 0; s < 8; s++) {
        int i = tid + (s << 10);
        int p = i ^ j;
        if (p > i) {
          u64 a = keys[i], c = keys[p];
          bool up = ((i & k) == 0);
          bool sw = up ? (a < c) : (a > c);  // descending overall
          if (sw) { keys[i] = c; keys[p] = a; }
        }
      }
      __syncthreads();
    }
  }
  for (int i = tid; i < NANCH; i += 1024) {
    u64 kk = keys[i];
    int orig = (int)(~(unsigned int)kk);
    order[b * NANCH + i] = orig;
    float4 p = *(const float4*)(props + ((size_t)b * NANCH + orig) * 4);
    *(float4*)(sb + ((size_t)b * NANCH + i) * 4) = p;
  }
}

// --------------------------- NMS bitmask (transposed u64) ------------------
// maskT[b][word cb][row i] (bit l = suppress col j=cb*64+l by row i, j>i);
// coalesced 8B-stride stores. Diagonals also in maskd[b][s][lane].
__global__ __launch_bounds__(64) void nms_mask_kernel(const float* __restrict__ sb,
                                                      u64* __restrict__ maskT,
                                                      u64* __restrict__ maskd) {
#pragma clang fp contract(off)
  int rb = blockIdx.x, cb = blockIdx.y, b = blockIdx.z;
  if (cb < rb) return;
  int lane = threadIdx.x;
  __shared__ float4 cbox[64];
  int j0 = cb << 6;
  const float* sbb = sb + (size_t)b * NANCH * 4;
  if (j0 + lane < NANCH) cbox[lane] = *(const float4*)(sbb + (size_t)(j0 + lane) * 4);
  __syncthreads();
  int i = (rb << 6) + lane;
  if (i >= NANCH) return;
  float4 rbox = *(const float4*)(sbb + (size_t)i * 4);
  float rarea = (rbox.z - rbox.x) * (rbox.w - rbox.y);
  u64 bits = 0ull;
  int jmax = NANCH - j0;
  if (jmax > 64) jmax = 64;
  for (int l = 0; l < jmax; l++) {
    int j = j0 + l;
    if (j > i) {
      float4 c = cbox[l];
      float carea = (c.z - c.x) * (c.w - c.y);
      float ltx = fmaxf(rbox.x, c.x), lty = fmaxf(rbox.y, c.y);
      float rbx = fminf(rbox.z, c.z), rby = fminf(rbox.w, c.w);
      float wx = fmaxf(rbx - ltx, 0.f);
      float wy = fmaxf(rby - lty, 0.f);
      float inter = wx * wy;
      float iou = inter / (rarea + carea - inter);  // 0/0 -> NaN -> compare false
      if (iou > 0.7f) bits |= (1ull << l);
    }
  }
  maskT[((size_t)b * NW + cb) * RSTR + i] = bits;
  if (rb == cb) maskd[((size_t)b * NW + rb) * 64 + lane] = bits;
}

// --------------------------- NMS scan (pipelined 16-wave) -------------------
// One 1024-thread block per batch. Double-buffered column in LDS.
// Stripe s: (1) ISSUE raw loads of column s+1 chunks (wave-strided; values
// consumed only in phase 4 -> loads stay in flight under phases 2-3);
// (2) masked reduce of column s from colbuf (keep-bit per chunk);
// (3) wave 0: combine + ctz chain on preloaded diagonal -> keep_sh[s];
// (4) ds_write column s+1 into the other buffer; barrier; swap.
__global__ __launch_bounds__(1024, 1) void nms_scan_kernel(const u64* __restrict__ maskT,
                                                           const u64* __restrict__ maskd,
                                                           const int* __restrict__ order,
                                                           const float* __restrict__ sb,
                                                           float* __restrict__ out) {
  int b = blockIdx.x;
  int tid = threadIdx.x;
  int lane = tid & 63, wv = tid >> 6;
  const u64* mt = maskT + (size_t)b * NW * RSTR;
  __shared__ u64 colbuf[2][NW * 64];  // 90112 B double-buffered column
  __shared__ u64 diag_sh[NW * 64];    // 45056 B diagonal words
  __shared__ u64 keep_sh[NW];
  __shared__ u64 cur_parts[NWAVES];

  // preload diagonals (coalesced, parallel)
  for (int i = tid; i < NW * 64; i += 1024)
    diag_sh[i] = maskd[(size_t)b * NW * 64 + i];
  __syncthreads();

  int cb = 0;
  for (int s = 0; s < NW; s++) {
    // ---- phase 1: issue raw gather of column s+1 (chunks 0..s) ----
    u64 g0 = 0, g1 = 0, g2 = 0, g3 = 0, g4 = 0, g5 = 0;
    if (s + 1 < NW) {
      const u64* coln = mt + (size_t)(s + 1) * RSTR + lane;
      if (wv      <= s) g0 = coln[(wv      ) << 6];
      if (wv + 16 <= s) g1 = coln[(wv + 16) << 6];
      if (wv + 32 <= s) g2 = coln[(wv + 32) << 6];
      if (wv + 48 <= s) g3 = coln[(wv + 48) << 6];
      if (wv + 64 <= s) g4 = coln[(wv + 64) << 6];
      if (wv + 80 <= s) g5 = coln[(wv + 80) << 6];
    }

    // ---- phase 2: masked reduce of column s from LDS ----
    u64 acc = 0ull;
    for (int c = wv; c < s; c += NWAVES) {
      u64 kw = keep_sh[c];
      u64 v = colbuf[cb][(c << 6) + lane];
      if ((kw >> lane) & 1ull) acc |= v;
    }
    acc = waveOr64(acc);
    if (lane == 0) cur_parts[wv] = acc;
    __syncthreads();

    // ---- phase 3: wave 0 combines + serial ctz chain ----
    if (wv == 0) {
      u64 p = (lane < NWAVES) ? cur_parts[lane] : 0ull;
      u64 cur = waveOr64(p);
      u64 Mw = diag_sh[(s << 6) + lane];  // row 64s+lane, word s
      int nrows = NANCH - (s << 6);
      if (nrows > 64) nrows = 64;
      u64 todo = ~cur;
      if (nrows < 64) todo &= (1ull << nrows) - 1ull;
      u64 alive = 0ull;
      while (todo) {
        int t = (int)__builtin_ctzll(todo);
        alive |= (1ull << t);
        todo &= ~(bcast64(Mw, t) | (1ull << t));
      }
      if (lane == 0) keep_sh[s] = alive;
    }

    // ---- phase 4: write gathered column s+1 (waitcnt lands here) ----
    if (s + 1 < NW) {
      u64* nb = colbuf[cb ^ 1];
      if (wv      <= s) nb[((wv      ) << 6) + lane] = g0;
      if (wv + 16 <= s) nb[((wv + 16) << 6) + lane] = g1;
      if (wv + 32 <= s) nb[((wv + 32) << 6) + lane] = g2;
      if (wv + 48 <= s) nb[((wv + 48) << 6) + lane] = g3;
      if (wv + 64 <= s) nb[((wv + 64) << 6) + lane] = g4;
      if (wv + 80 <= s) nb[((wv + 80) << 6) + lane] = g5;
    }
    __syncthreads();
    cb ^= 1;
  }

  // write output: out[b][orig] = kept ? sorted_box : 0
  for (int i = tid; i < NANCH; i += 1024) {
    u64 kw = keep_sh[i >> 6];
    bool kept = ((kw >> (i & 63)) & 1ull) != 0ull;
    int orig = order[b * NANCH + i];
    float4 p = *(const float4*)(sb + ((size_t)b * NANCH + i) * 4);
    float4 o = kept ? p : make_float4(0.f, 0.f, 0.f, 0.f);
    *(float4*)(out + ((size_t)b * NANCH + orig) * 4) = o;
  }
}

// --------------------------- host launcher ---------------------------------

extern "C" void kernel_launch(void* const* d_in, const int* in_sizes, int n_in,
                              void* d_out, int out_size, void* d_ws, size_t ws_size,
                              hipStream_t stream) {
  const float* features = (const float*)d_in[0];
  const float* conv_w   = (const float*)d_in[1];
  const float* conv_b   = (const float*)d_in[2];
  const float* cls_w    = (const float*)d_in[3];
  const float* cls_b    = (const float*)d_in[4];
  const float* bbox_w   = (const float*)d_in[5];
  const float* bbox_b   = (const float*)d_in[6];
  const int*   img_h    = (const int*)d_in[7];
  const int*   img_w    = (const int*)d_in[8];
  float* out = (float*)d_out;
  char* ws = (char*)d_ws;

  // workspace layout (bytes); mask arrays alias FM/WT/XP (dead by NMS time)
  const size_t OFF_FM    = 0;                  // 5,120,000
  const size_t OFF_WT    = 5120000;            // 9,437,184
  const size_t OFF_XP    = 14557184;           // 15,360,000 (ends 29,917,184)
  const size_t OFF_MASKT = 0;                  // 15,859,712 (aliases FM/WT/XP-head)
  const size_t OFF_MASKD = 15859712;           // 180,224 (inside dead XP)
  const size_t OFF_X2  = 29917184;             // 5,120,000
  const size_t OFF_WCO = 35037184;             // 131,072
  const size_t OFF_BCO = 35168256;             // 256
  const size_t OFF_LOG = 35168512;             // 640,000
  const size_t OFF_SC  = 35808512;             // 90,000
  const size_t OFF_PR  = 35898512;             // 360,000
  const size_t OFF_ORD = 36258512;             // 90,000
  const size_t OFF_SB  = 36348512;             // 360,000
  const size_t WS_NEEDED = 36708512;
  if (ws_size < WS_NEEDED) return;

  float* fm   = (float*)(ws + OFF_FM);
  float* Wt   = (float*)(ws + OFF_WT);
  float* xp   = (float*)(ws + OFF_XP);
  u64*   maskT = (u64*)(ws + OFF_MASKT);
  u64*   maskd = (u64*)(ws + OFF_MASKD);
  float* x2   = (float*)(ws + OFF_X2);
  float* Wco  = (float*)(ws + OFF_WCO);
  float* bco  = (float*)(ws + OFF_BCO);
  float* logits = (float*)(ws + OFF_LOG);
  float* scores = (float*)(ws + OFF_SC);
  float* props  = (float*)(ws + OFF_PR);
  int*   order  = (int*)(ws + OFF_ORD);
  float* sb     = (float*)(ws + OFF_SB);

  // base anchors in double, rounded to f32 exactly like numpy
  BaseAnchors ba;
  {
    const double scales[3] = {64.0, 128.0, 256.0};
    const double ratios[3] = {0.5, 1.0, 2.0};
    int a = 0;
    for (int si = 0; si < 3; si++)
      for (int ri = 0; ri < 3; ri++, a++) {
        double w = scales[si] * sqrt(ratios[ri]);
        double h = scales[si] / sqrt(ratios[ri]);
        ba.x1[a] = (float)(-w / 2.0);
        ba.y1[a] = (float)(-h / 2.0);
        ba.x2[a] = (float)(w / 2.0);
        ba.y2[a] = (float)(h / 2.0);
      }
  }

  transpose_features<<<dim3(20, 16, 4), dim3(32, 8), 0, stream>>>(features, fm);
  transpose_weights<<<dim3(16, 16), 256, 0, stream>>>(conv_w, Wt);
  build_wco<<<128, 256, 0, stream>>>(cls_w, cls_b, bbox_w, bbox_b, Wco, bco);
  conv_gemm<<<dim3(40, 8, 3), 256, 0, stream>>>(fm, Wt, xp);
  combine_relu<<<1250, 256, 0, stream>>>(xp, conv_b, x2);
  gemm1x1<<<40, 256, 0, stream>>>(x2, Wco, bco, logits);
  score_box_kernel<<<88, 256, 0, stream>>>(logits, img_h, img_w, ba, scores, props);
  sort_kernel<<<4, 1024, 0, stream>>>(scores, props, order, sb);
  nms_mask_kernel<<<dim3(NW, NW, 4), 64, 0, stream>>>(sb, maskT, maskd);
  nms_scan_kernel<<<4, 1024, 0, stream>>>(maskT, maskd, order, sb, out);
}

// Round 8
// 487.072 us; speedup vs baseline: 1.5317x; 1.5317x over previous
//
#include <hip/hip_runtime.h>

// ---------------------------------------------------------------------------
// RPN forward: conv3x3(512->512)+relu, 1x1 heads (18 cls, 36 bbox),
// anchor decode + clip, softmax score, greedy NMS (0.7), keep-masked boxes.
// All decision math in fp32 with contraction OFF to track the numpy reference.
// R8: SPARSE NMS. Mask kernel appends nonzero off-diagonal (bits,row) entries
//   to per-(b,colword) lists (atomic; OR commutative -> deterministic).
//   Scan = ONE wave, no barriers: per stripe one coalesced list load +
//   keep-bit mask + shuffle-OR, then ctz chain over ONLY rows with nonzero
//   diagonal out-edges (ballot filter).
//   History: R1 517 scratch; R2/R3 655/536 serialized loads; R4 434 asm
//   batches; R5 WRONG (global_load_lds same-wave); R6 372 16-wave dense;
//   R7 372 pipelining NEUTRAL -> serial reduce/chain/barriers dominate.
// ---------------------------------------------------------------------------

#define NBATCH 4
#define HWDIM  25
#define NPOS   625            // 25*25
#define NM     2500           // NBATCH*NPOS
#define CIN    512
#define NANCH  5625           // NPOS*9
#define NW     88             // ceil(NANCH/64)
#define CAP    4096           // list capacity per (b, colword)

typedef unsigned long long u64;
typedef unsigned int u32;

struct BaseAnchors { float x1[9], y1[9], x2[9], y2[9]; };

__device__ __forceinline__ u64 bcast64(u64 v, int lane) {
  unsigned int lo = (unsigned int)v;
  unsigned int hi = (unsigned int)(v >> 32);
  lo = (unsigned int)__builtin_amdgcn_readlane((int)lo, lane);
  hi = (unsigned int)__builtin_amdgcn_readlane((int)hi, lane);
  return (((u64)hi) << 32) | (u64)lo;
}

__device__ __forceinline__ u64 waveOr64(u64 x) {
  unsigned int lo = (unsigned int)x, hi = (unsigned int)(x >> 32);
#pragma unroll
  for (int off = 32; off > 0; off >>= 1) {
    lo |= (unsigned int)__shfl_xor((int)lo, off, 64);
    hi |= (unsigned int)__shfl_xor((int)hi, off, 64);
  }
  return (((u64)hi) << 32) | (u64)lo;
}

// --------------------------- prep: transposes ------------------------------

// f[b][c][pos] -> fm[b*625+pos][c]
__global__ void transpose_features(const float* __restrict__ f, float* __restrict__ fm) {
  __shared__ float tile[32][33];
  int b  = blockIdx.z;
  int p0 = blockIdx.x * 32;
  int c0 = blockIdx.y * 32;
  int tx = threadIdx.x, ty = threadIdx.y;  // (32, 8)
#pragma unroll
  for (int j = 0; j < 4; j++) {
    int c = c0 + ty + j * 8;
    int p = p0 + tx;
    if (p < NPOS) tile[ty + j * 8][tx] = f[((size_t)(b * CIN + c)) * NPOS + p];
  }
  __syncthreads();
#pragma unroll
  for (int j = 0; j < 4; j++) {
    int p = p0 + ty + j * 8;
    int c = c0 + tx;
    if (p < NPOS) fm[((size_t)(b * NPOS + p)) * CIN + c] = tile[tx][ty + j * 8];
  }
}

// conv_w[o][c][tap] -> Wt[tap][c][o]
__global__ __launch_bounds__(256) void transpose_weights(const float* __restrict__ cw,
                                                         float* __restrict__ Wt) {
  __shared__ float tile[32][289];
  int o0 = blockIdx.x * 32, c0 = blockIdx.y * 32;
  int tid = threadIdx.x;
#pragma unroll
  for (int j = 0; j < 36; j++) {
    int idx = tid + j * 256;            // 0..9215
    int o = idx / 288, kk = idx % 288;  // kk = c_rel*9 + tap
    tile[o][kk] = cw[((size_t)(o0 + o)) * 4608 + c0 * 9 + kk];
  }
  __syncthreads();
  int ol = tid & 31, pg = tid >> 5;  // 0..7
#pragma unroll
  for (int j = 0; j < 36; j++) {
    int pair = pg + j * 8;  // 0..287 == c_rel*9 + tap
    int c = pair / 9, tap = pair % 9;
    Wt[((size_t)tap * CIN + (c0 + c)) * 512 + o0 + ol] = tile[ol][pair];
  }
}

// combined 1x1 head weights: Wco[c][o] (o: 0..17 cls, 18..53 bbox, 54..63 zero)
__global__ void build_wco(const float* __restrict__ clsw, const float* __restrict__ clsb,
                          const float* __restrict__ bw, const float* __restrict__ bbb,
                          float* __restrict__ Wco, float* __restrict__ bco) {
  int idx = blockIdx.x * 256 + threadIdx.x;
  if (idx < 512 * 64) {
    int c = idx >> 6, o = idx & 63;
    float v = 0.f;
    if (o < 18) v = clsw[o * 512 + c];
    else if (o < 54) v = bw[(o - 18) * 512 + c];
    Wco[idx] = v;
  }
  if (idx < 64) {
    float v = 0.f;
    if (idx < 18) v = clsb[idx];
    else if (idx < 54) v = bbb[idx - 18];
    bco[idx] = v;
  }
}

__global__ void zero_cnt(u32* __restrict__ cnt) {
  int i = blockIdx.x * 64 + threadIdx.x;
  if (i < NBATCH * NW) cnt[i] = 0u;
}

// --------------------------- conv3x3 implicit GEMM -------------------------
// grid (40, 8, 3): 64 m-rows x 64 o-cols per block, part = 3 taps (dy fixed).
// Writes partial sums (no bias/relu) to xp[part][m][o].
__global__ __launch_bounds__(256) void conv_gemm(const float* __restrict__ fm,
                                                 const float* __restrict__ Wt,
                                                 float* __restrict__ xp) {
  __shared__ __align__(16) float At[32][68];
  __shared__ __align__(16) float Bt[32][64];
  int tid = threadIdx.x;
  int m0 = blockIdx.x << 6;
  int o0 = blockIdx.y << 6;
  int part = blockIdx.z;  // 0..2 -> dy = part-1
  int ti = tid >> 4, tj = tid & 15;   // compute tile 4x4
  int si = tid >> 2, sq = tid & 3;    // A staging: row si, col quad sq
  int skk = tid >> 3, sr = tid & 7;   // B staging: k-row skk, col oct sr
  float acc[4][4] = {{0.f}};

  int m = m0 + si;
  bool mv = m < NM;
  int mm = mv ? m : 0;
  int bb = mm / NPOS, rem = mm % NPOS;
  int hh = rem / HWDIM, ww = rem % HWDIM;
  int dy = part - 1;

  for (int tt = 0; tt < 3; tt++) {
    int tap = part * 3 + tt;
    int dx = tt - 1;
    int h2 = hh + dy, w2 = ww + dx;
    bool av = mv && ((unsigned)h2 < (unsigned)HWDIM) && ((unsigned)w2 < (unsigned)HWDIM);
    const float* arow = fm + (((size_t)(bb * NPOS + h2 * HWDIM + w2)) << 9);
    const float* bbase = Wt + (((size_t)tap) << 18) + o0;
    for (int c0 = 0; c0 < CIN; c0 += 32) {
      __syncthreads();
      float4 a0 = make_float4(0.f, 0.f, 0.f, 0.f), a1 = a0;
      if (av) {
        a0 = *(const float4*)(arow + c0 + (sq << 2));
        a1 = *(const float4*)(arow + c0 + 16 + (sq << 2));
      }
      int kb = sq << 2;
      At[kb + 0][si] = a0.x; At[kb + 1][si] = a0.y; At[kb + 2][si] = a0.z; At[kb + 3][si] = a0.w;
      At[kb + 16][si] = a1.x; At[kb + 17][si] = a1.y; At[kb + 18][si] = a1.z; At[kb + 19][si] = a1.w;
      const float* bp = bbase + (((size_t)(c0 + skk)) << 9);
      *(float4*)&Bt[skk][sr << 2] = *(const float4*)(bp + (sr << 2));
      *(float4*)&Bt[skk][32 + (sr << 2)] = *(const float4*)(bp + 32 + (sr << 2));
      __syncthreads();
#pragma unroll
      for (int kk = 0; kk < 32; kk++) {
        float4 avv = *(const float4*)&At[kk][ti << 2];
        float4 bvv = *(const float4*)&Bt[kk][tj << 2];
        float a_[4] = {avv.x, avv.y, avv.z, avv.w};
        float b_[4] = {bvv.x, bvv.y, bvv.z, bvv.w};
#pragma unroll
        for (int u = 0; u < 4; u++)
#pragma unroll
          for (int v = 0; v < 4; v++) acc[u][v] += a_[u] * b_[v];
      }
    }
  }
  float* outp = xp + (size_t)part * (NM * 512);
#pragma unroll
  for (int u = 0; u < 4; u++) {
    int mr = m0 + (ti << 2) + u;
    if (mr < NM) {
      float4 r = make_float4(acc[u][0], acc[u][1], acc[u][2], acc[u][3]);
      *(float4*)(outp + (((size_t)mr) << 9) + o0 + (tj << 2)) = r;
    }
  }
}

// x2 = relu(xp0+xp1+xp2+bias)
__global__ void combine_relu(const float* __restrict__ xp, const float* __restrict__ bias,
                             float* __restrict__ x2) {
  int i4 = blockIdx.x * 256 + threadIdx.x;  // over 320000 float4s
  if (i4 >= NM * 128) return;
  float4 p0 = *(const float4*)(xp + (size_t)i4 * 4);
  float4 p1 = *(const float4*)(xp + (size_t)(NM * 512) + (size_t)i4 * 4);
  float4 p2 = *(const float4*)(xp + (size_t)(2 * NM * 512) + (size_t)i4 * 4);
  float4 bb = *(const float4*)(bias + (i4 & 127) * 4);
  float4 r;
  r.x = fmaxf(p0.x + p1.x + p2.x + bb.x, 0.f);
  r.y = fmaxf(p0.y + p1.y + p2.y + bb.y, 0.f);
  r.z = fmaxf(p0.z + p1.z + p2.z + bb.z, 0.f);
  r.w = fmaxf(p0.w + p1.w + p2.w + bb.w, 0.f);
  *(float4*)(x2 + (size_t)i4 * 4) = r;
}

// --------------------------- 1x1 heads GEMM --------------------------------
// logits[m][0..63] = x2[m][:] @ Wco + bco   (grid 40)
__global__ __launch_bounds__(256) void gemm1x1(const float* __restrict__ x2,
                                               const float* __restrict__ Wco,
                                               const float* __restrict__ bco,
                                               float* __restrict__ logits) {
  __shared__ __align__(16) float At[32][68];
  __shared__ __align__(16) float Bt[32][64];
  int tid = threadIdx.x;
  int m0 = blockIdx.x << 6;
  int ti = tid >> 4, tj = tid & 15;
  int si = tid >> 2, sq = tid & 3;
  int skk = tid >> 3, sr = tid & 7;
  float acc[4][4] = {{0.f}};
  int m = m0 + si;
  bool mv = m < NM;
  const float* arow = x2 + (((size_t)(mv ? m : 0)) << 9);
  for (int c0 = 0; c0 < CIN; c0 += 32) {
    __syncthreads();
    float4 a0 = make_float4(0.f, 0.f, 0.f, 0.f), a1 = a0;
    if (mv) {
      a0 = *(const float4*)(arow + c0 + (sq << 2));
      a1 = *(const float4*)(arow + c0 + 16 + (sq << 2));
    }
    int kb = sq << 2;
    At[kb + 0][si] = a0.x; At[kb + 1][si] = a0.y; At[kb + 2][si] = a0.z; At[kb + 3][si] = a0.w;
    At[kb + 16][si] = a1.x; At[kb + 17][si] = a1.y; At[kb + 18][si] = a1.z; At[kb + 19][si] = a1.w;
    const float* bp = Wco + (size_t)(c0 + skk) * 64;
    *(float4*)&Bt[skk][sr << 2] = *(const float4*)(bp + (sr << 2));
    *(float4*)&Bt[skk][32 + (sr << 2)] = *(const float4*)(bp + 32 + (sr << 2));
    __syncthreads();
#pragma unroll
    for (int kk = 0; kk < 32; kk++) {
      float4 avv = *(const float4*)&At[kk][ti << 2];
      float4 bvv = *(const float4*)&Bt[kk][tj << 2];
      float a_[4] = {avv.x, avv.y, avv.z, avv.w};
      float b_[4] = {bvv.x, bvv.y, bvv.z, bvv.w};
#pragma unroll
      for (int u = 0; u < 4; u++)
#pragma unroll
        for (int v = 0; v < 4; v++) acc[u][v] += a_[u] * b_[v];
    }
  }
  float4 bias = *(const float4*)(bco + (tj << 2));
#pragma unroll
  for (int u = 0; u < 4; u++) {
    int mr = m0 + (ti << 2) + u;
    if (mr < NM) {
      float4 r = make_float4(acc[u][0] + bias.x, acc[u][1] + bias.y, acc[u][2] + bias.z,
                             acc[u][3] + bias.w);
      *(float4*)(logits + (size_t)mr * 64 + (tj << 2)) = r;
    }
  }
}

// --------------------------- scores + proposals ----------------------------
__global__ __launch_bounds__(256) void score_box_kernel(const float* __restrict__ logits,
                                                        const int* __restrict__ ih,
                                                        const int* __restrict__ iw,
                                                        BaseAnchors ba,
                                                        float* __restrict__ scores,
                                                        float* __restrict__ props) {
#pragma clang fp contract(off)
  int n = blockIdx.x * 256 + threadIdx.x;
  if (n >= NBATCH * NANCH) return;
  int b = n / NANCH;
  int r = n % NANCH;
  int pos = r / 9, aa = r % 9;
  int py = pos / HWDIM, px = pos % HWDIM;
  const float* L = logits + (size_t)(b * NPOS + pos) * 64;
  float l0 = L[2 * aa], l1 = L[2 * aa + 1];
  float mx = fmaxf(l0, l1);
  float e0 = expf(l0 - mx), e1 = expf(l1 - mx);
  float s = e1 / (e0 + e1);
  float d0 = L[18 + 4 * aa + 0], d1 = L[18 + 4 * aa + 1];
  float d2 = L[18 + 4 * aa + 2], d3 = L[18 + 4 * aa + 3];
  float xf = (float)px * 32.f, yf = (float)py * 32.f;
  float ax1 = ba.x1[aa] + xf, ay1 = ba.y1[aa] + yf;
  float ax2 = ba.x2[aa] + xf, ay2 = ba.y2[aa] + yf;
  float wA = ax2 - ax1, hA = ay2 - ay1;
  float cx = ax1 + 0.5f * wA, cy = ay1 + 0.5f * hA;
  float pcx = d0 * wA + cx, pcy = d1 * hA + cy;
  float pw = expf(d2) * wA, ph = expf(d3) * hA;
  float x1 = pcx - 0.5f * pw, y1 = pcy - 0.5f * ph;
  float x2 = pcx + 0.5f * pw, y2 = pcy + 0.5f * ph;
  float W = (float)iw[0], H = (float)ih[0];
  x1 = fminf(fmaxf(x1, 0.f), W);
  y1 = fminf(fmaxf(y1, 0.f), H);
  x2 = fminf(fmaxf(x2, 0.f), W);
  y2 = fminf(fmaxf(y2, 0.f), H);
  scores[n] = s;
  *(float4*)(props + (size_t)n * 4) = make_float4(x1, y1, x2, y2);
}

// --------------------------- sort (bitonic, stable ties) -------------------
__global__ __launch_bounds__(1024) void sort_kernel(const float* __restrict__ scores,
                                                    const float* __restrict__ props,
                                                    int* __restrict__ order,
                                                    float* __restrict__ sb) {
  __shared__ u64 keys[8192];
  int b = blockIdx.x, tid = threadIdx.x;
  const float* sc = scores + (size_t)b * NANCH;
  for (int i = tid; i < 8192; i += 1024) {
    u64 k = 0ull;
    if (i < NANCH) {
      unsigned int sbits = __float_as_uint(sc[i]);  // scores > 0 -> order-preserving bits
      k = (((u64)sbits) << 32) | (u64)(~(unsigned int)i);
    }
    keys[i] = k;
  }
  __syncthreads();
  for (int k = 2; k <= 8192; k <<= 1) {
    for (int j = k >> 1; j > 0; j >>= 1) {
#pragma unroll
      for (int s = 0; s < 8; s++) {
        int i = tid + (s << 10);
        int p = i ^ j;
        if (p > i) {
          u64 a = keys[i], c = keys[p];
          bool up = ((i & k) == 0);
          bool sw = up ? (a < c) : (a > c);  // descending overall
          if (sw) { keys[i] = c; keys[p] = a; }
        }
      }
      __syncthreads();
    }
  }
  for (int i = tid; i < NANCH; i += 1024) {
    u64 kk = keys[i];
    int orig = (int)(~(unsigned int)kk);
    order[b * NANCH + i] = orig;
    float4 p = *(const float4*)(props + ((size_t)b * NANCH + orig) * 4);
    *(float4*)(sb + ((size_t)b * NANCH + i) * 4) = p;
  }
}

// --------------------------- NMS bitmask (SPARSE lists) --------------------
// Off-diagonal nonzero words appended to lists[b][cb]: (bitsLo, bitsHi, row).
// Append order nondeterministic (atomics) but consumption is a masked OR ->
// result deterministic. Diagonal blocks stored dense in maskd[b][s][lane].
__global__ __launch_bounds__(64) void nms_mask_kernel(const float* __restrict__ sb,
                                                      uint4* __restrict__ lists,
                                                      u32* __restrict__ cnt,
                                                      u64* __restrict__ maskd) {
#pragma clang fp contract(off)
  int rb = blockIdx.x, cb = blockIdx.y, b = blockIdx.z;
  if (cb < rb) return;
  int lane = threadIdx.x;
  __shared__ float4 cbox[64];
  int j0 = cb << 6;
  const float* sbb = sb + (size_t)b * NANCH * 4;
  if (j0 + lane < NANCH) cbox[lane] = *(const float4*)(sbb + (size_t)(j0 + lane) * 4);
  __syncthreads();
  int i = (rb << 6) + lane;
  if (i >= NANCH) return;
  float4 rbox = *(const float4*)(sbb + (size_t)i * 4);
  float rarea = (rbox.z - rbox.x) * (rbox.w - rbox.y);
  u64 bits = 0ull;
  int jmax = NANCH - j0;
  if (jmax > 64) jmax = 64;
  for (int l = 0; l < jmax; l++) {
    int j = j0 + l;
    if (j > i) {
      float4 c = cbox[l];
      float carea = (c.z - c.x) * (c.w - c.y);
      float ltx = fmaxf(rbox.x, c.x), lty = fmaxf(rbox.y, c.y);
      float rbx = fminf(rbox.z, c.z), rby = fminf(rbox.w, c.w);
      float wx = fmaxf(rbx - ltx, 0.f);
      float wy = fmaxf(rby - lty, 0.f);
      float inter = wx * wy;
      float iou = inter / (rarea + carea - inter);  // 0/0 -> NaN -> compare false
      if (iou > 0.7f) bits |= (1ull << l);
    }
  }
  if (rb == cb) {
    maskd[((size_t)b * NW + rb) * 64 + lane] = bits;
  } else if (bits) {
    u32 idx = atomicAdd(&cnt[b * NW + cb], 1u);
    if (idx < CAP)
      lists[((size_t)(b * NW + cb)) * CAP + idx] =
          make_uint4((u32)bits, (u32)(bits >> 32), (u32)i, 0u);
  }
}

// --------------------------- NMS scan (sparse, 1 wave, no barriers) --------
// Per stripe s: cur = OR over list entries (coalesced uint4 load, keep-bit
// checked via LDS keep words), shuffle-OR reduce; then ctz chain over ONLY
// rows with nonzero diagonal out-edges (ballot-filtered). Rows without
// out-edges are decided by the final ~cur. Single wave -> no barriers.
__global__ __launch_bounds__(64, 1) void nms_scan_kernel(const uint4* __restrict__ lists,
                                                         const u32* __restrict__ cnt,
                                                         const u64* __restrict__ maskd,
                                                         const int* __restrict__ order,
                                                         const float* __restrict__ sb,
                                                         float* __restrict__ out) {
  int b = blockIdx.x;
  int lane = threadIdx.x;
  __shared__ u64 keep_sh[NW];
  const u64* md = maskd + (size_t)b * NW * 64;
  const uint4* lb = lists + (size_t)b * NW * CAP;

  // counts into registers: lane l holds cnt[l] and cnt[l+64]
  u32 c0 = (lane < NW) ? cnt[b * NW + lane] : 0u;
  u32 c1 = (lane + 64 < NW) ? cnt[b * NW + lane + 64] : 0u;

  u64 diag = md[lane];  // stripe 0 diagonal (coalesced)
  for (int s = 0; s < NW; s++) {
    u64 Mw = diag;
    if (s + 1 < NW) diag = md[((s + 1) << 6) + lane];  // loop-carried prefetch

    int cn = (int)(u32)__builtin_amdgcn_readlane(
        (int)((s < 64) ? c0 : c1), (s < 64) ? s : s - 64);
    if (cn > CAP) cn = CAP;

    // gather: OR keep-masked list entries
    u64 acc = 0ull;
    for (int p = lane; p < cn; p += 64) {
      uint4 e = lb[(size_t)s * CAP + p];
      u64 kw = keep_sh[e.z >> 6];
      if ((kw >> (e.z & 63)) & 1ull) acc |= (((u64)e.y) << 32) | (u64)e.x;
    }
    u64 cur = waveOr64(acc);

    int nrows = NANCH - (s << 6);
    if (nrows > 64) nrows = 64;
    u64 valid = (nrows < 64) ? ((1ull << nrows) - 1ull) : ~0ull;

    // chain over rows with nonzero out-edges only
    u64 nz = __ballot(Mw != 0ull);
    u64 todo = nz & ~cur & valid;
    while (todo) {
      int t = (int)__builtin_ctzll(todo);
      cur |= bcast64(Mw, t);
      todo &= ~cur;
      todo &= ~(1ull << t);
    }
    u64 alive = (~cur) & valid;
    if (lane == 0) keep_sh[s] = alive;  // same-wave LDS, no barrier needed
  }

  // write output: out[b][orig] = kept ? sorted_box : 0
  for (int i = lane; i < NANCH; i += 64) {
    u64 kw = keep_sh[i >> 6];
    bool kept = ((kw >> (i & 63)) & 1ull) != 0ull;
    int orig = order[b * NANCH + i];
    float4 p = *(const float4*)(sb + ((size_t)b * NANCH + i) * 4);
    float4 o = kept ? p : make_float4(0.f, 0.f, 0.f, 0.f);
    *(float4*)(out + ((size_t)b * NANCH + orig) * 4) = o;
  }
}

// --------------------------- host launcher ---------------------------------

extern "C" void kernel_launch(void* const* d_in, const int* in_sizes, int n_in,
                              void* d_out, int out_size, void* d_ws, size_t ws_size,
                              hipStream_t stream) {
  const float* features = (const float*)d_in[0];
  const float* conv_w   = (const float*)d_in[1];
  const float* conv_b   = (const float*)d_in[2];
  const float* cls_w    = (const float*)d_in[3];
  const float* cls_b    = (const float*)d_in[4];
  const float* bbox_w   = (const float*)d_in[5];
  const float* bbox_b   = (const float*)d_in[6];
  const int*   img_h    = (const int*)d_in[7];
  const int*   img_w    = (const int*)d_in[8];
  float* out = (float*)d_out;
  char* ws = (char*)d_ws;

  // workspace layout (bytes); NMS arrays alias FM/WT/XP (dead by NMS time)
  const size_t OFF_FM    = 0;                  // 5,120,000
  const size_t OFF_WT    = 5120000;            // 9,437,184
  const size_t OFF_XP    = 14557184;           // 15,360,000 (ends 29,917,184)
  const size_t OFF_LISTS = 0;                  // 23,068,672 (4*88*4096*16)
  const size_t OFF_CNT   = 23068672;           // 1,408 -> pad to 23,070,208
  const size_t OFF_MASKD = 23070208;           // 180,224 (ends 23,250,432)
  const size_t OFF_X2  = 29917184;             // 5,120,000
  const size_t OFF_WCO = 35037184;             // 131,072
  const size_t OFF_BCO = 35168256;             // 256
  const size_t OFF_LOG = 35168512;             // 640,000
  const size_t OFF_SC  = 35808512;             // 90,000
  const size_t OFF_PR  = 35898512;             // 360,000
  const size_t OFF_ORD = 36258512;             // 90,000
  const size_t OFF_SB  = 36348512;             // 360,000
  const size_t WS_NEEDED = 36708512;
  if (ws_size < WS_NEEDED) return;

  float* fm   = (float*)(ws + OFF_FM);
  float* Wt   = (float*)(ws + OFF_WT);
  float* xp   = (float*)(ws + OFF_XP);
  uint4* lists = (uint4*)(ws + OFF_LISTS);
  u32*   cnt   = (u32*)(ws + OFF_CNT);
  u64*   maskd = (u64*)(ws + OFF_MASKD);
  float* x2   = (float*)(ws + OFF_X2);
  float* Wco  = (float*)(ws + OFF_WCO);
  float* bco  = (float*)(ws + OFF_BCO);
  float* logits = (float*)(ws + OFF_LOG);
  float* scores = (float*)(ws + OFF_SC);
  float* props  = (float*)(ws + OFF_PR);
  int*   order  = (int*)(ws + OFF_ORD);
  float* sb     = (float*)(ws + OFF_SB);

  // base anchors in double, rounded to f32 exactly like numpy
  BaseAnchors ba;
  {
    const double scales[3] = {64.0, 128.0, 256.0};
    const double ratios[3] = {0.5, 1.0, 2.0};
    int a = 0;
    for (int si = 0; si < 3; si++)
      for (int ri = 0; ri < 3; ri++, a++) {
        double w = scales[si] * sqrt(ratios[ri]);
        double h = scales[si] / sqrt(ratios[ri]);
        ba.x1[a] = (float)(-w / 2.0);
        ba.y1[a] = (float)(-h / 2.0);
        ba.x2[a] = (float)(w / 2.0);
        ba.y2[a] = (float)(h / 2.0);
      }
  }

  transpose_features<<<dim3(20, 16, 4), dim3(32, 8), 0, stream>>>(features, fm);
  transpose_weights<<<dim3(16, 16), 256, 0, stream>>>(conv_w, Wt);
  build_wco<<<128, 256, 0, stream>>>(cls_w, cls_b, bbox_w, bbox_b, Wco, bco);
  conv_gemm<<<dim3(40, 8, 3), 256, 0, stream>>>(fm, Wt, xp);
  combine_relu<<<1250, 256, 0, stream>>>(xp, conv_b, x2);
  gemm1x1<<<40, 256, 0, stream>>>(x2, Wco, bco, logits);
  score_box_kernel<<<88, 256, 0, stream>>>(logits, img_h, img_w, ba, scores, props);
  sort_kernel<<<4, 1024, 0, stream>>>(scores, props, order, sb);
  zero_cnt<<<6, 64, 0, stream>>>(cnt);
  nms_mask_kernel<<<dim3(NW, NW, 4), 64, 0, stream>>>(sb, lists, cnt, maskd);
  nms_scan_kernel<<<4, 64, 0, stream>>>(lists, cnt, maskd, order, sb, out);
}